// Round 4
// baseline (240.202 us; speedup 1.0000x reference)
//
#include <hip/hip_runtime.h>
#include <hip/hip_bf16.h>
#include <math.h>

#define NV 64
#define ND 64
#define NTOK 8192
#define LN_EPS 1e-5f
#define SROW 4096
#define WROW 4096
#define BK 64
#define NKC2 (4096 / BK)        // 64: full-K loop in fused stage2
#define MT 32                   // fused stage2 token tile -> grid 256

typedef __attribute__((ext_vector_type(8))) short s8v;    // 8 bf16 = 4 VGPR
typedef __attribute__((ext_vector_type(4))) float f4v;    // MFMA C/D
typedef __attribute__((ext_vector_type(4))) int   i4v;

__device__ __forceinline__ float sigm_f(float x) {
    return __builtin_amdgcn_rcpf(1.f + __expf(-x));
}
__device__ __forceinline__ float elu_f(float x)  { return x > 0.f ? x : (__expf(x) - 1.f); }

__device__ __forceinline__ float bf16_to_f(unsigned short s) {
    union { unsigned int u; float f; } c; c.u = ((unsigned int)s) << 16;
    return c.f;
}
__device__ __forceinline__ unsigned short bf16_rn(float f) {
    union { float f; unsigned int u; } c; c.f = f;
    return (unsigned short)((c.u + 0x8000u) >> 16);
}
// async global->LDS 16B (lds base wave-uniform; lane l writes base + l*16B)
__device__ __forceinline__ void async16(const void* g, void* l) {
    __builtin_amdgcn_global_load_lds(
        (const __attribute__((address_space(1))) unsigned int*)g,
        (__attribute__((address_space(3))) unsigned int*)l,
        16, 0, 0);
}

// ---------------- Prepack: weight transposes via LDS tiles (coalesced R+W)
// b<64: W2/Wg per-v transposes -> bf16 w2b/wgb
// 64<=b<192: wct[n][k] = [Wn1|Wns]^T bf16
// b>=192: Wn2T/WngT f32 transposes (for fused tail float4 dots)
__global__ __launch_bounds__(256) void vsn_prepack(
    const float* __restrict__ W2, const float* __restrict__ Wg,
    const float* __restrict__ Wn1, const float* __restrict__ Wns,
    const float* __restrict__ Wn2, const float* __restrict__ Wng,
    short* __restrict__ w2b, short* __restrict__ wgb,
    short* __restrict__ wct,
    float* __restrict__ Wn2T, float* __restrict__ WngT)
{
    __shared__ float T[64][65];
    const int b = blockIdx.x, t = threadIdx.x;

    if (b < 64) {
        const float* src = W2 + (size_t)b * 4096;
        short* dst = w2b + (size_t)b * 4096;
        #pragma unroll
        for (int pass = 0; pass < 2; ++pass) {
            #pragma unroll
            for (int i = 0; i < 16; ++i) {
                int id = i * 256 + t;
                T[id & 63][id >> 6] = src[id];
            }
            __syncthreads();
            #pragma unroll
            for (int i = 0; i < 16; ++i) {
                int id = i * 256 + t;
                dst[id] = (short)bf16_rn(T[id >> 6][id & 63]);
            }
            __syncthreads();
            src = Wg + (size_t)b * 4096;
            dst = wgb + (size_t)b * 4096;
        }
    } else if (b < 192) {
        int tb = b - 64;
        int half = tb >> 6, kt = tb & 63;
        const float* src = (half == 0 ? Wn1 : Wns) + (size_t)(kt * 64) * 64;
        #pragma unroll
        for (int i = 0; i < 16; ++i) {
            int id = i * 256 + t;
            T[id & 63][id >> 6] = src[id];
        }
        __syncthreads();
        #pragma unroll
        for (int i = 0; i < 16; ++i) {
            int id = i * 256 + t;
            int n = id >> 6, r = id & 63;
            wct[(size_t)(half * 64 + n) * WROW + kt * 64 + r] = (short)bf16_rn(T[n][r]);
        }
    } else {
        const float* src = (b == 192 ? Wn2 : Wng);
        float* dst = (b == 192 ? Wn2T : WngT);
        #pragma unroll
        for (int i = 0; i < 16; ++i) {
            int id = i * 256 + t;
            T[id & 63][id >> 6] = src[id];      // T[j][k] = src[k*64+j]
        }
        __syncthreads();
        #pragma unroll
        for (int i = 0; i < 16; ++i) {
            int id = i * 256 + t;
            dst[id] = T[id >> 6][id & 63];      // dst[j][k] = src[k][j]
        }
    }
}

// ---------------- Stage 1: verified round-0 version (~50us). UNCHANGED.
__global__ __launch_bounds__(256) void vsn_stage1(
    const float* __restrict__ x,
    const float* __restrict__ W1, const float* __restrict__ b1,
    const short* __restrict__ w2b, const short* __restrict__ wgb,
    const float* __restrict__ b2, const float* __restrict__ bg,
    const float* __restrict__ Wsk, const float* __restrict__ bsk,
    const float* __restrict__ gamma, const float* __restrict__ beta,
    unsigned short* __restrict__ stb)
{
    const int t = threadIdx.x;
    const int wave = t >> 6, lane = t & 63;
    const int m16 = lane & 15, quad = lane >> 4;
    const int v = blockIdx.y * 4 + wave;

    __shared__ float xs[4][32];
    __shared__ __align__(16) unsigned short h2s[4][32][72];

    float w1k[2][8], b1k[2][8];
    #pragma unroll
    for (int kt = 0; kt < 2; ++kt) {
        *(float4*)&w1k[kt][0] = *(const float4*)(W1 + v * 64 + kt * 32 + quad * 8);
        *(float4*)&w1k[kt][4] = *(const float4*)(W1 + v * 64 + kt * 32 + quad * 8 + 4);
        *(float4*)&b1k[kt][0] = *(const float4*)(b1 + v * 64 + kt * 32 + quad * 8);
        *(float4*)&b1k[kt][4] = *(const float4*)(b1 + v * 64 + kt * 32 + quad * 8 + 4);
    }
    float b2d[4], bgd[4], wskd[4], bskd[4], gamd[4], betd[4];
    #pragma unroll
    for (int ni = 0; ni < 4; ++ni) {
        int d = v * 64 + ni * 16 + m16;
        b2d[ni] = b2[d]; bgd[ni] = bg[d]; wskd[ni] = Wsk[d]; bskd[ni] = bsk[d];
        gamd[ni] = gamma[d]; betd[ni] = beta[d];
    }
    const size_t wb = (size_t)v * 4096;

    for (int tt4 = 0; tt4 < 4; ++tt4) {
        const int tile0 = blockIdx.x * 128 + tt4 * 32;

        if (lane < 32) xs[wave][lane] = x[(size_t)(tile0 + lane) * NV + v];

        s8v a[2][2];
        #pragma unroll
        for (int kt = 0; kt < 2; ++kt)
            #pragma unroll
            for (int mi = 0; mi < 2; ++mi) {
                float xv = xs[wave][mi * 16 + m16];
                float h[8];
                #pragma unroll
                for (int j = 0; j < 8; ++j) h[j] = elu_f(fmaf(xv, w1k[kt][j], b1k[kt][j]));
                i4v av;
                #pragma unroll
                for (int p = 0; p < 4; ++p) {
                    unsigned int u0 = __float_as_uint(h[2 * p]);
                    unsigned int u1 = __float_as_uint(h[2 * p + 1]);
                    av[p] = (int)((u1 & 0xffff0000u) | (u0 >> 16));
                }
                a[mi][kt] = *(s8v*)&av;
            }

        f4v hacc[2][4];
        #pragma unroll
        for (int mi = 0; mi < 2; ++mi)
            #pragma unroll
            for (int ni = 0; ni < 4; ++ni) hacc[mi][ni] = (f4v){0.f, 0.f, 0.f, 0.f};
        #pragma unroll
        for (int ni = 0; ni < 4; ++ni)
            #pragma unroll
            for (int kt = 0; kt < 2; ++kt) {
                s8v bh = *(const s8v*)(w2b + wb + (size_t)(ni * 16 + m16) * 64 + kt * 32 + quad * 8);
                #pragma unroll
                for (int mi = 0; mi < 2; ++mi)
                    hacc[mi][ni] = __builtin_amdgcn_mfma_f32_16x16x32_bf16(a[mi][kt], bh, hacc[mi][ni], 0, 0, 0);
            }
        #pragma unroll
        for (int mi = 0; mi < 2; ++mi)
            #pragma unroll
            for (int ni = 0; ni < 4; ++ni)
                #pragma unroll
                for (int r = 0; r < 4; ++r) hacc[mi][ni][r] += b2d[ni];

        #pragma unroll
        for (int mi = 0; mi < 2; ++mi)
            #pragma unroll
            for (int ni = 0; ni < 4; ++ni)
                #pragma unroll
                for (int r = 0; r < 4; ++r)
                    h2s[wave][mi * 16 + quad * 4 + r][ni * 16 + m16] =
                        (unsigned short)(__float_as_uint(hacc[mi][ni][r]) >> 16);

        s8v c[2][2];
        #pragma unroll
        for (int mi = 0; mi < 2; ++mi)
            #pragma unroll
            for (int kt = 0; kt < 2; ++kt)
                c[mi][kt] = *(const s8v*)&h2s[wave][mi * 16 + m16][kt * 32 + quad * 8];

        f4v gacc[2][4];
        #pragma unroll
        for (int mi = 0; mi < 2; ++mi)
            #pragma unroll
            for (int ni = 0; ni < 4; ++ni) gacc[mi][ni] = (f4v){0.f, 0.f, 0.f, 0.f};
        #pragma unroll
        for (int ni = 0; ni < 4; ++ni)
            #pragma unroll
            for (int kt = 0; kt < 2; ++kt) {
                s8v bh = *(const s8v*)(wgb + wb + (size_t)(ni * 16 + m16) * 64 + kt * 32 + quad * 8);
                #pragma unroll
                for (int mi = 0; mi < 2; ++mi)
                    gacc[mi][ni] = __builtin_amdgcn_mfma_f32_16x16x32_bf16(c[mi][kt], bh, gacc[mi][ni], 0, 0, 0);
            }

        {
            float xtok[2][4];
            #pragma unroll
            for (int mi = 0; mi < 2; ++mi)
                #pragma unroll
                for (int r = 0; r < 4; ++r) xtok[mi][r] = xs[wave][mi * 16 + quad * 4 + r];
            #pragma unroll
            for (int mi = 0; mi < 2; ++mi)
                #pragma unroll
                for (int ni = 0; ni < 4; ++ni)
                    #pragma unroll
                    for (int r = 0; r < 4; ++r) {
                        float g = sigm_f(gacc[mi][ni][r] + bgd[ni]);
                        gacc[mi][ni][r] = fmaf(xtok[mi][r], wskd[ni], bskd[ni]) + g * hacc[mi][ni][r];
                    }
        }

        #pragma unroll
        for (int mi = 0; mi < 2; ++mi)
            #pragma unroll
            for (int r = 0; r < 4; ++r) {
                float s0 = gacc[mi][0][r], s1 = gacc[mi][1][r], s2 = gacc[mi][2][r], s3 = gacc[mi][3][r];
                float sum = s0 + s1 + s2 + s3;
                float sq  = s0 * s0 + s1 * s1 + s2 * s2 + s3 * s3;
                #pragma unroll
                for (int m = 1; m < 16; m <<= 1) { sum += __shfl_xor(sum, m); sq += __shfl_xor(sq, m); }
                float mu  = sum * 0.015625f;
                float var = sq * 0.015625f - mu * mu;
                float rs  = __builtin_amdgcn_rsqf(var + LN_EPS);
                size_t base = (size_t)(tile0 + mi * 16 + quad * 4 + r) * SROW + (size_t)v * 64 + m16;
                #pragma unroll
                for (int ni = 0; ni < 4; ++ni)
                    stb[base + ni * 16] =
                        bf16_rn((gacc[mi][ni][r] - mu) * rs * gamd[ni] + betd[ni]);
            }
    }
}

// ---------------- FUSED Stage 2: full-K GEMM (M=32, N=128, K=4096) + tail GRN
// + softmax + weighted sum, one block per 32 tokens. Grid 256 = 1 block/CU.
// K-loop = round-3-verified distance-2 prefetch + counted vmcnt; LDS overlay
// (staging 40KB | tail 43.5KB). Eliminates `part` (64 MiB RW) + stb re-read
// + one launch.
__global__ __launch_bounds__(512) void vsn_stage2(
    const unsigned short* __restrict__ stb,   // [8192][SROW]
    const short* __restrict__ wct,            // [128][WROW]
    const float* __restrict__ Wn2T, const float* __restrict__ WngT,
    const float* __restrict__ bn1, const float* __restrict__ bn2,
    const float* __restrict__ bng, const float* __restrict__ bns,
    const float* __restrict__ ngamma, const float* __restrict__ nbeta,
    float* __restrict__ out)
{
    const int t = threadIdx.x;
    const int wave = t >> 6, lane = t & 63;
    const int m16 = lane & 15, quad = lane >> 4;
    const int tok0 = blockIdx.x * MT;

    // ---- LDS overlay: staging [0,40960) ; tail [0,43520)
    __shared__ __align__(16) unsigned char smem[43520];
    unsigned short* Al0 = (unsigned short*)smem;             // [2][32*64]
    unsigned short* Bl0 = (unsigned short*)(smem + 8192);    // [2][128*64]
    float* hw1_s = (float*)smem;                             // [32][68]
    float* skw_s = (float*)(smem + 8704);
    float* hw2_s = (float*)(smem + 17408);
    float* s2_s  = (float*)(smem + 26112);
    float* w_s   = (float*)(smem + 34816);

    f4v acc[2];
    acc[0] = (f4v){0.f, 0.f, 0.f, 0.f};
    acc[1] = (f4v){0.f, 0.f, 0.f, 0.f};

    // staging: B 2 calls/wave (16 rows), A 1 call for waves 0-3 (8 rows each)
    auto STAGE = [&](int buf, int kc) {
        const int kb = kc * BK;
        #pragma unroll
        for (int q = 0; q < 2; ++q) {
            const int row = wave * 16 + q * 8 + (lane >> 3);
            const int sc = ((lane & 7) ^ (row & 7)) * 8;     // inverse swizzle
            async16(wct + (size_t)row * WROW + kb + sc,
                    &Bl0[buf * 8192 + wave * 1024 + q * 512]);
        }
        if (wave < 4) {
            const int row = wave * 8 + (lane >> 3);
            const int sc = ((lane & 7) ^ (row & 7)) * 8;
            async16(stb + (size_t)(tok0 + row) * SROW + kb + sc,
                    &Al0[buf * 2048 + wave * 512]);
        }
    };

    STAGE(0, 0);
    STAGE(1, 1);

    for (int kc = 0; kc < NKC2; ++kc) {
        const int buf = kc & 1;
        if (kc + 1 < NKC2) {
            if (wave < 4) asm volatile("s_waitcnt vmcnt(3)" ::: "memory");
            else          asm volatile("s_waitcnt vmcnt(2)" ::: "memory");
        } else {
            asm volatile("s_waitcnt vmcnt(0)" ::: "memory");
        }
        __builtin_amdgcn_s_barrier();
        __builtin_amdgcn_sched_barrier(0);

        #pragma unroll
        for (int ks = 0; ks < 2; ++ks) {
            s8v af[2], bf1;
            #pragma unroll
            for (int mi = 0; mi < 2; ++mi) {
                int row = mi * 16 + m16;
                int ch = ((ks * 4 + quad) ^ (row & 7)) * 8;  // swizzled read
                af[mi] = *(const s8v*)&Al0[buf * 2048 + row * 64 + ch];
            }
            {
                int row = wave * 16 + m16;
                int ch = ((ks * 4 + quad) ^ (row & 7)) * 8;
                bf1 = *(const s8v*)&Bl0[buf * 8192 + row * 64 + ch];
            }
            acc[0] = __builtin_amdgcn_mfma_f32_16x16x32_bf16(af[0], bf1, acc[0], 0, 0, 0);
            acc[1] = __builtin_amdgcn_mfma_f32_16x16x32_bf16(af[1], bf1, acc[1], 0, 0, 0);
        }

        asm volatile("s_waitcnt lgkmcnt(0)" ::: "memory");
        __builtin_amdgcn_s_barrier();
        __builtin_amdgcn_sched_barrier(0);
        if (kc + 2 < NKC2) STAGE(buf, kc + 2);
    }

    // ---- T0: registers -> hw1_s / skw_s (LDS overlay now owns smem)
    if (wave < 4) {
        const int col = wave * 16 + m16;
        const float bb = bn1[col];
        #pragma unroll
        for (int mi = 0; mi < 2; ++mi)
            #pragma unroll
            for (int r = 0; r < 4; ++r)
                hw1_s[(mi * 16 + quad * 4 + r) * 68 + col] = elu_f(acc[mi][r] + bb);
    } else {
        const int col = (wave - 4) * 16 + m16;
        const float bb = bns[col];
        #pragma unroll
        for (int mi = 0; mi < 2; ++mi)
            #pragma unroll
            for (int r = 0; r < 4; ++r)
                skw_s[(mi * 16 + quad * 4 + r) * 68 + col] = acc[mi][r] + bb;
    }
    __syncthreads();

    // ---- T1: hw2 = hw1 @ Wn2 + bn2  (32x64, K=64; Wn2T float4 dots)
    #pragma unroll
    for (int i = 0; i < 4; ++i) {
        int oidx = i * 512 + t;
        int tt = oidx >> 6, jj = oidx & 63;
        float a = bn2[jj];
        #pragma unroll
        for (int k4 = 0; k4 < 16; ++k4) {
            float4 h = *(const float4*)&hw1_s[tt * 68 + k4 * 4];
            float4 w4 = *(const float4*)(Wn2T + jj * 64 + k4 * 4);
            a += h.x * w4.x + h.y * w4.y + h.z * w4.z + h.w * w4.w;
        }
        hw2_s[tt * 68 + jj] = a;
    }
    __syncthreads();

    // ---- T2: gw = sigmoid(hw2 @ Wng + bng); s2 = skw + gw*hw2
    #pragma unroll
    for (int i = 0; i < 4; ++i) {
        int oidx = i * 512 + t;
        int tt = oidx >> 6, vv = oidx & 63;
        float a = bng[vv];
        #pragma unroll
        for (int k4 = 0; k4 < 16; ++k4) {
            float4 h = *(const float4*)&hw2_s[tt * 68 + k4 * 4];
            float4 w4 = *(const float4*)(WngT + vv * 64 + k4 * 4);
            a += h.x * w4.x + h.y * w4.y + h.z * w4.z + h.w * w4.w;
        }
        float gw = sigm_f(a);
        s2_s[tt * 68 + vv] = skw_s[tt * 68 + vv] + gw * hw2_s[tt * 68 + vv];
    }
    __syncthreads();

    // ---- T3: LN over v + softmax; 16 lanes per token, 32 tokens, all 512 thr
    {
        int tt = t >> 4, l = t & 15;
        float z[4]; float sum = 0.f, sq = 0.f;
        #pragma unroll
        for (int i = 0; i < 4; ++i) { z[i] = s2_s[tt * 68 + l + 16 * i]; sum += z[i]; sq += z[i] * z[i]; }
        #pragma unroll
        for (int m = 1; m < 16; m <<= 1) { sum += __shfl_xor(sum, m); sq += __shfl_xor(sq, m); }
        float mu  = sum * 0.015625f;
        float var = sq * 0.015625f - mu * mu;
        float rs  = __builtin_amdgcn_rsqf(var + LN_EPS);
        float ln[4]; float mx = -1e30f;
        #pragma unroll
        for (int i = 0; i < 4; ++i) {
            ln[i] = (z[i] - mu) * rs * ngamma[l + 16 * i] + nbeta[l + 16 * i];
            mx = fmaxf(mx, ln[i]);
        }
        #pragma unroll
        for (int m = 1; m < 16; m <<= 1) mx = fmaxf(mx, __shfl_xor(mx, m));
        float es = 0.f; float ev[4];
        #pragma unroll
        for (int i = 0; i < 4; ++i) { ev[i] = __expf(ln[i] - mx); es += ev[i]; }
        #pragma unroll
        for (int m = 1; m < 16; m <<= 1) es += __shfl_xor(es, m);
        float inv = __builtin_amdgcn_rcpf(es);
        #pragma unroll
        for (int i = 0; i < 4; ++i) w_s[tt * 68 + l + 16 * i] = ev[i] * inv;
    }
    __syncthreads();

    // ---- T4: weighted sum; wave handles 4 tokens; stb tile is L2-hot
    {
        const int vloc = lane >> 3, d8 = (lane & 7) * 8;
        #pragma unroll
        for (int tk = 0; tk < 4; ++tk) {
            const int tl = wave * 4 + tk;
            const unsigned short* s0 = stb + (size_t)(tok0 + tl) * SROW + d8;
            float a[8];
            #pragma unroll
            for (int j = 0; j < 8; ++j) a[j] = 0.f;
            #pragma unroll
            for (int vc = 0; vc < 8; ++vc) {
                int v = vc * 8 + vloc;
                float w = w_s[tl * 68 + v];
                s8v rr = *(const s8v*)(s0 + v * 64);
                #pragma unroll
                for (int j = 0; j < 8; ++j)
                    a[j] = fmaf(w, bf16_to_f((unsigned short)rr[j]), a[j]);
            }
            #pragma unroll
            for (int m = 8; m <= 32; m <<= 1)
                #pragma unroll
                for (int j = 0; j < 8; ++j) a[j] += __shfl_xor(a[j], m);
            if (lane < 8) {
                float* op = out + (size_t)(tok0 + tl) * 64 + lane * 8;
                *(float4*)op       = make_float4(a[0], a[1], a[2], a[3]);
                *(float4*)(op + 4) = make_float4(a[4], a[5], a[6], a[7]);
            }
        }
    }
}

extern "C" void kernel_launch(void* const* d_in, const int* in_sizes, int n_in,
                              void* d_out, int out_size, void* d_ws, size_t ws_size,
                              hipStream_t stream) {
    const float* x     = (const float*)d_in[0];
    const float* W1    = (const float*)d_in[1];
    const float* b1    = (const float*)d_in[2];
    const float* W2    = (const float*)d_in[3];
    const float* b2    = (const float*)d_in[4];
    const float* Wg    = (const float*)d_in[5];
    const float* bg    = (const float*)d_in[6];
    const float* Wsk   = (const float*)d_in[7];
    const float* bsk   = (const float*)d_in[8];
    const float* gamma = (const float*)d_in[9];
    const float* beta  = (const float*)d_in[10];
    const float* Wn1   = (const float*)d_in[11];
    const float* bn1   = (const float*)d_in[12];
    const float* Wn2   = (const float*)d_in[13];
    const float* bn2   = (const float*)d_in[14];
    const float* Wng   = (const float*)d_in[15];
    const float* bng   = (const float*)d_in[16];
    const float* Wns   = (const float*)d_in[17];
    const float* bns   = (const float*)d_in[18];
    const float* ngam  = (const float*)d_in[19];
    const float* nbet  = (const float*)d_in[20];

    char* ws = (char*)d_ws;
    unsigned short* stb = (unsigned short*)ws;                   // 64 MiB
    short* wct = (short*)(ws + (64u << 20));                     // 1 MiB
    short* w2b = (short*)(ws + (65u << 20));                     // 512 KiB each
    short* wgb = w2b + 262144;
    float* Wn2T = (float*)(ws + (66u << 20));                    // 16 KiB
    float* WngT = Wn2T + 4096;                                   // 16 KiB
    float* outp = (float*)d_out;

    vsn_prepack<<<dim3(194), 256, 0, stream>>>(W2, Wg, Wn1, Wns, Wn2, Wng,
                                               w2b, wgb, wct, Wn2T, WngT);
    vsn_stage1<<<dim3(NTOK / 128, 16), 256, 0, stream>>>(
        x, W1, b1, w2b, wgb, b2, bg, Wsk, bsk, gamma, beta, stb);
    vsn_stage2<<<dim3(NTOK / MT), 512, 0, stream>>>(
        stb, wct, Wn2T, WngT, bn1, bn2, bng, bns, ngam, nbet, outp);
}